// Round 2
// baseline (211.772 us; speedup 1.0000x reference)
//
#include <hip/hip_runtime.h>
#include <stdint.h>

#define TABLE_MASK 0x7FFFFu          // TABLE_SIZE = 524288 = 2^19
#define PRIME 2654435761u
#define WORDS_PER_TABLE 65536        // 524288 entries * 4 bits / 32

// ---------------------------------------------------------------------------
// Pack kernel: binarize three (524288,4) f32 tables into 4-bit nibbles.
// Entry e -> word e>>3, bit (e&7)*4 + f. Bit set <=> table value >= 0 (+1).
// (reference: b = sign(t) + (sign(t)==0) => +1 for t>=0 incl -0.0, -1 for t<0)
// ---------------------------------------------------------------------------
__global__ __launch_bounds__(256) void pack_kernel(
    const float* __restrict__ t0, const float* __restrict__ t1,
    const float* __restrict__ t2, uint32_t* __restrict__ out) {
  uint32_t tid = blockIdx.x * 256u + threadIdx.x;   // 0 .. 3*65536-1
  uint32_t tab = tid >> 16;
  uint32_t word = tid & 65535u;
  const float4* t =
      (const float4*)(tab == 0 ? t0 : (tab == 1 ? t1 : t2)) + word * 8u;
  uint32_t v = 0;
#pragma unroll
  for (int k = 0; k < 8; ++k) {
    float4 f = t[k];
    uint32_t n = (f.x >= 0.0f ? 1u : 0u) | (f.y >= 0.0f ? 2u : 0u) |
                 (f.z >= 0.0f ? 4u : 0u) | (f.w >= 0.0f ? 8u : 0u);
    v |= n << (4 * k);
  }
  out[tid] = v;
}

// ---------------------------------------------------------------------------
// Per-plane accumulate of "sum of weights whose sign-bit is set" (p).
// Plane contribution = 2*p - 1 (weights sum to 1); folded into epilogue.
// Corner merge trick: i10 = i00 ^ d, i11 = i01 ^ d with d = ia^(ia+1);
// when d < 8 (7/8 of lanes) the +x corners share the packed word -> skip load.
// ---------------------------------------------------------------------------
__device__ __forceinline__ void plane_accum(
    const uint32_t* __restrict__ t, float a, float b,
    float& p0, float& p1, float& p2, float& p3) {
  float sa = a * 512.0f, sb = b * 512.0f;
  float fa = floorf(sa), fb = floorf(sb);
  float wa = sa - fa, wb = sb - fb;
  uint32_t ia = (uint32_t)fa, ib = (uint32_t)fb;
  uint32_t hb0 = ib * PRIME;
  uint32_t hb1 = hb0 + PRIME;
  uint32_t i00 = (ia ^ hb0) & TABLE_MASK;
  uint32_t i01 = (ia ^ hb1) & TABLE_MASK;
  uint32_t d = ia ^ (ia + 1u);              // low-bit mask, >=8 for 1/8 of ia
  uint32_t i10 = i00 ^ d;                   // == ((ia+1)^hb0)&MASK
  uint32_t i11 = i01 ^ d;
  uint32_t w00 = t[i00 >> 3];
  uint32_t w01 = t[i01 >> 3];
  uint32_t w10 = w00, w11 = w01;
  if (d >= 8u) {                            // ~1/8 lanes take the extra loads
    w10 = t[i10 >> 3];
    w11 = t[i11 >> 3];
  }
  uint32_t n00 = w00 >> ((i00 & 7u) * 4u);
  uint32_t n01 = w01 >> ((i01 & 7u) * 4u);
  uint32_t n10 = w10 >> ((i10 & 7u) * 4u);
  uint32_t n11 = w11 >> ((i11 & 7u) * 4u);
  float omwa = 1.0f - wa, omwb = 1.0f - wb;
  float v00 = omwa * omwb, v01 = omwa * wb, v10 = wa * omwb, v11 = wa * wb;
// masked add: mask = sign-extended bit f of nibble; float & mask is w or 0
#define ACC(NIB, WGT)                                                         \
  p0 += __uint_as_float(__float_as_uint(WGT) &                                \
                        (uint32_t)__builtin_amdgcn_sbfe((int)(NIB), 0, 1));   \
  p1 += __uint_as_float(__float_as_uint(WGT) &                                \
                        (uint32_t)__builtin_amdgcn_sbfe((int)(NIB), 1, 1));   \
  p2 += __uint_as_float(__float_as_uint(WGT) &                                \
                        (uint32_t)__builtin_amdgcn_sbfe((int)(NIB), 2, 1));   \
  p3 += __uint_as_float(__float_as_uint(WGT) &                                \
                        (uint32_t)__builtin_amdgcn_sbfe((int)(NIB), 3, 1));
  ACC(n00, v00)
  ACC(n01, v01)
  ACC(n10, v10)
  ACC(n11, v11)
#undef ACC
}

__global__ __launch_bounds__(256) void hash_main(
    const float* __restrict__ pos, const uint32_t* __restrict__ pk,
    float4* __restrict__ out, int n) {
  int i = (int)(blockIdx.x * 256u + threadIdx.x);
  if (i >= n) return;
  float x = pos[3 * i + 0];
  float y = pos[3 * i + 1];
  float z = pos[3 * i + 2];
  float p0 = 0.f, p1 = 0.f, p2 = 0.f, p3 = 0.f;
  plane_accum(pk, x, y, p0, p1, p2, p3);
  plane_accum(pk + WORDS_PER_TABLE, x, z, p0, p1, p2, p3);
  plane_accum(pk + 2 * WORDS_PER_TABLE, y, z, p0, p1, p2, p3);
  float4 o;
  o.x = fmaf(2.0f, p0, -3.0f);   // sum over 3 planes of (2*p_plane - 1)
  o.y = fmaf(2.0f, p1, -3.0f);
  o.z = fmaf(2.0f, p2, -3.0f);
  o.w = fmaf(2.0f, p3, -3.0f);
  out[i] = o;
}

// ---------------------------------------------------------------------------
// Fallback (ws too small): gather f32 features directly, binarize on the fly.
// ---------------------------------------------------------------------------
__device__ __forceinline__ void plane_accum_f(
    const float4* __restrict__ t, float a, float b,
    float& p0, float& p1, float& p2, float& p3) {
  float sa = a * 512.0f, sb = b * 512.0f;
  float fa = floorf(sa), fb = floorf(sb);
  float wa = sa - fa, wb = sb - fb;
  uint32_t ia = (uint32_t)fa, ib = (uint32_t)fb;
  uint32_t hb0 = ib * PRIME;
  uint32_t hb1 = hb0 + PRIME;
  uint32_t i00 = (ia ^ hb0) & TABLE_MASK;
  uint32_t i01 = (ia ^ hb1) & TABLE_MASK;
  uint32_t i10 = ((ia + 1u) ^ hb0) & TABLE_MASK;
  uint32_t i11 = ((ia + 1u) ^ hb1) & TABLE_MASK;
  float4 f00 = t[i00], f01 = t[i01], f10 = t[i10], f11 = t[i11];
  float omwa = 1.0f - wa, omwb = 1.0f - wb;
  float v00 = omwa * omwb, v01 = omwa * wb, v10 = wa * omwb, v11 = wa * wb;
#define ACCF(F, W)                                                            \
  p0 += ((F).x >= 0.0f) ? (W) : 0.0f;                                         \
  p1 += ((F).y >= 0.0f) ? (W) : 0.0f;                                         \
  p2 += ((F).z >= 0.0f) ? (W) : 0.0f;                                         \
  p3 += ((F).w >= 0.0f) ? (W) : 0.0f;
  ACCF(f00, v00)
  ACCF(f01, v01)
  ACCF(f10, v10)
  ACCF(f11, v11)
#undef ACCF
}

__global__ __launch_bounds__(256) void hash_direct(
    const float* __restrict__ pos, const float4* __restrict__ txy,
    const float4* __restrict__ txz, const float4* __restrict__ tyz,
    float4* __restrict__ out, int n) {
  int i = (int)(blockIdx.x * 256u + threadIdx.x);
  if (i >= n) return;
  float x = pos[3 * i + 0];
  float y = pos[3 * i + 1];
  float z = pos[3 * i + 2];
  float p0 = 0.f, p1 = 0.f, p2 = 0.f, p3 = 0.f;
  plane_accum_f(txy, x, y, p0, p1, p2, p3);
  plane_accum_f(txz, x, z, p0, p1, p2, p3);
  plane_accum_f(tyz, y, z, p0, p1, p2, p3);
  float4 o;
  o.x = fmaf(2.0f, p0, -3.0f);
  o.y = fmaf(2.0f, p1, -3.0f);
  o.z = fmaf(2.0f, p2, -3.0f);
  o.w = fmaf(2.0f, p3, -3.0f);
  out[i] = o;
}

extern "C" void kernel_launch(void* const* d_in, const int* in_sizes, int n_in,
                              void* d_out, int out_size, void* d_ws,
                              size_t ws_size, hipStream_t stream) {
  const float* pos = (const float*)d_in[0];
  const float* txy = (const float*)d_in[1];
  const float* txz = (const float*)d_in[2];
  const float* tyz = (const float*)d_in[3];
  float4* out = (float4*)d_out;
  int n = in_sizes[0] / 3;                       // 4194304
  int nblk = (n + 255) / 256;
  if (ws_size >= (size_t)3 * WORDS_PER_TABLE * 4) {
    uint32_t* pk = (uint32_t*)d_ws;
    pack_kernel<<<3 * WORDS_PER_TABLE / 256, 256, 0, stream>>>(txy, txz, tyz,
                                                               pk);
    hash_main<<<nblk, 256, 0, stream>>>(pos, pk, out, n);
  } else {
    hash_direct<<<nblk, 256, 0, stream>>>(pos, (const float4*)txy,
                                          (const float4*)txz,
                                          (const float4*)tyz, out, n);
  }
}

// Round 3
// 181.713 us; speedup vs baseline: 1.1654x; 1.1654x over previous
//
#include <hip/hip_runtime.h>
#include <stdint.h>

#define TABLE_MASK 0x7FFFFu          // TABLE_SIZE = 524288 = 2^19
#define PRIME 2654435761u
#define WORDS_PER_TABLE 65536        // 524288 entries * 4 bits / 32
#define CELLS_PER_PLANE (512 * 512)  // 262144 cells, uint16 each

// ---------------------------------------------------------------------------
// Stage 1: binarize three (524288,4) f32 tables into 4-bit nibbles.
// Entry e -> word e>>3, nibble (e&7); bit f set <=> table[e][f] >= 0 (+1).
// ---------------------------------------------------------------------------
__global__ __launch_bounds__(256) void pack_kernel(
    const float* __restrict__ t0, const float* __restrict__ t1,
    const float* __restrict__ t2, uint32_t* __restrict__ out) {
  uint32_t tid = blockIdx.x * 256u + threadIdx.x;   // 0 .. 3*65536-1
  uint32_t tab = tid >> 16;
  uint32_t word = tid & 65535u;
  const float4* t =
      (const float4*)(tab == 0 ? t0 : (tab == 1 ? t1 : t2)) + word * 8u;
  uint32_t v = 0;
#pragma unroll
  for (int k = 0; k < 8; ++k) {
    float4 f = t[k];
    uint32_t n = (f.x >= 0.0f ? 1u : 0u) | (f.y >= 0.0f ? 2u : 0u) |
                 (f.z >= 0.0f ? 4u : 0u) | (f.w >= 0.0f ? 8u : 0u);
    v |= n << (4 * k);
  }
  out[tid] = v;
}

// ---------------------------------------------------------------------------
// Stage 2: per-cell corner records. For plane p, cell (ia, ib) in [0,512)^2,
// gather the 4 corner nibbles via the hash and pack into one uint16:
// bits [0:3]=n(ia,ib) [4:7]=n(ia,ib+1) [8:11]=n(ia+1,ib) [12:15]=n(ia+1,ib+1)
// (corner order matches reference _OFFSETS / weight stacking).
// ---------------------------------------------------------------------------
__global__ __launch_bounds__(256) void cellify_kernel(
    const uint32_t* __restrict__ pk, uint16_t* __restrict__ cells) {
  uint32_t tid = blockIdx.x * 256u + threadIdx.x;   // 0 .. 3*262144-1
  uint32_t plane = tid >> 18;
  uint32_t ia = (tid >> 9) & 511u;
  uint32_t ib = tid & 511u;
  const uint32_t* t = pk + plane * WORDS_PER_TABLE;
  uint32_t hb0 = ib * PRIME;
  uint32_t hb1 = hb0 + PRIME;                       // (ib+1)*PRIME (wraps ok)
  uint32_t i00 = (ia ^ hb0) & TABLE_MASK;
  uint32_t i01 = (ia ^ hb1) & TABLE_MASK;
  uint32_t i10 = ((ia + 1u) ^ hb0) & TABLE_MASK;
  uint32_t i11 = ((ia + 1u) ^ hb1) & TABLE_MASK;
  uint32_t n00 = (t[i00 >> 3] >> ((i00 & 7u) * 4u)) & 15u;
  uint32_t n01 = (t[i01 >> 3] >> ((i01 & 7u) * 4u)) & 15u;
  uint32_t n10 = (t[i10 >> 3] >> ((i10 & 7u) * 4u)) & 15u;
  uint32_t n11 = (t[i11 >> 3] >> ((i11 & 7u) * 4u)) & 15u;
  cells[tid] = (uint16_t)(n00 | (n01 << 4) | (n10 << 8) | (n11 << 12));
}

// ---------------------------------------------------------------------------
// Stage 3: main kernel — ONE gather per plane per point from the cell table.
// Accumulate p_f = sum of weights whose sign bit is +; out = 2p - 3.
// ---------------------------------------------------------------------------
__device__ __forceinline__ float bitmask_w(float w, uint32_t r, int bit) {
  // w if bit set else 0, branch-free: float & sign-extended bit
  return __uint_as_float(__float_as_uint(w) &
                         (uint32_t)__builtin_amdgcn_sbfe((int)r, bit, 1));
}

__device__ __forceinline__ void plane_cell(
    const uint16_t* __restrict__ cells, float a, float b,
    float& p0, float& p1, float& p2, float& p3) {
  float sa = a * 512.0f, sb = b * 512.0f;
  float fa = floorf(sa), fb = floorf(sb);
  float wa = sa - fa, wb = sb - fb;
  uint32_t ia = (uint32_t)fa, ib = (uint32_t)fb;
  uint32_t r = cells[(ia << 9) | ib];
  float omwa = 1.0f - wa, omwb = 1.0f - wb;
  float v00 = omwa * omwb, v01 = omwa * wb, v10 = wa * omwb, v11 = wa * wb;
#define ACC4(W, C)                                                            \
  p0 += bitmask_w((W), r, (C)*4 + 0);                                         \
  p1 += bitmask_w((W), r, (C)*4 + 1);                                         \
  p2 += bitmask_w((W), r, (C)*4 + 2);                                         \
  p3 += bitmask_w((W), r, (C)*4 + 3);
  ACC4(v00, 0)
  ACC4(v01, 1)
  ACC4(v10, 2)
  ACC4(v11, 3)
#undef ACC4
}

__global__ __launch_bounds__(256) void hash_main(
    const float* __restrict__ pos, const uint16_t* __restrict__ cells,
    float4* __restrict__ out, int n) {
  int i = (int)(blockIdx.x * 256u + threadIdx.x);
  if (i >= n) return;
  float x = pos[3 * i + 0];
  float y = pos[3 * i + 1];
  float z = pos[3 * i + 2];
  float p0 = 0.f, p1 = 0.f, p2 = 0.f, p3 = 0.f;
  plane_cell(cells, x, y, p0, p1, p2, p3);
  plane_cell(cells + CELLS_PER_PLANE, x, z, p0, p1, p2, p3);
  plane_cell(cells + 2 * CELLS_PER_PLANE, y, z, p0, p1, p2, p3);
  float4 o;
  o.x = fmaf(2.0f, p0, -3.0f);   // sum over 3 planes of (2*p_plane - 1)
  o.y = fmaf(2.0f, p1, -3.0f);
  o.z = fmaf(2.0f, p2, -3.0f);
  o.w = fmaf(2.0f, p3, -3.0f);
  out[i] = o;
}

// ---------------------------------------------------------------------------
// Fallback A (ws fits pack only): gather packed nibbles directly (round-2 path)
// ---------------------------------------------------------------------------
__device__ __forceinline__ void plane_accum(
    const uint32_t* __restrict__ t, float a, float b,
    float& p0, float& p1, float& p2, float& p3) {
  float sa = a * 512.0f, sb = b * 512.0f;
  float fa = floorf(sa), fb = floorf(sb);
  float wa = sa - fa, wb = sb - fb;
  uint32_t ia = (uint32_t)fa, ib = (uint32_t)fb;
  uint32_t hb0 = ib * PRIME;
  uint32_t hb1 = hb0 + PRIME;
  uint32_t i00 = (ia ^ hb0) & TABLE_MASK;
  uint32_t i01 = (ia ^ hb1) & TABLE_MASK;
  uint32_t d = ia ^ (ia + 1u);
  uint32_t i10 = i00 ^ d;
  uint32_t i11 = i01 ^ d;
  uint32_t w00 = t[i00 >> 3];
  uint32_t w01 = t[i01 >> 3];
  uint32_t w10 = w00, w11 = w01;
  if (d >= 8u) {
    w10 = t[i10 >> 3];
    w11 = t[i11 >> 3];
  }
  uint32_t n00 = w00 >> ((i00 & 7u) * 4u);
  uint32_t n01 = w01 >> ((i01 & 7u) * 4u);
  uint32_t n10 = w10 >> ((i10 & 7u) * 4u);
  uint32_t n11 = w11 >> ((i11 & 7u) * 4u);
  float omwa = 1.0f - wa, omwb = 1.0f - wb;
  float v00 = omwa * omwb, v01 = omwa * wb, v10 = wa * omwb, v11 = wa * wb;
#define ACCN(NIB, WGT)                                                        \
  p0 += bitmask_w((WGT), (NIB), 0);                                           \
  p1 += bitmask_w((WGT), (NIB), 1);                                           \
  p2 += bitmask_w((WGT), (NIB), 2);                                           \
  p3 += bitmask_w((WGT), (NIB), 3);
  ACCN(n00, v00)
  ACCN(n01, v01)
  ACCN(n10, v10)
  ACCN(n11, v11)
#undef ACCN
}

__global__ __launch_bounds__(256) void hash_packed(
    const float* __restrict__ pos, const uint32_t* __restrict__ pk,
    float4* __restrict__ out, int n) {
  int i = (int)(blockIdx.x * 256u + threadIdx.x);
  if (i >= n) return;
  float x = pos[3 * i + 0];
  float y = pos[3 * i + 1];
  float z = pos[3 * i + 2];
  float p0 = 0.f, p1 = 0.f, p2 = 0.f, p3 = 0.f;
  plane_accum(pk, x, y, p0, p1, p2, p3);
  plane_accum(pk + WORDS_PER_TABLE, x, z, p0, p1, p2, p3);
  plane_accum(pk + 2 * WORDS_PER_TABLE, y, z, p0, p1, p2, p3);
  float4 o;
  o.x = fmaf(2.0f, p0, -3.0f);
  o.y = fmaf(2.0f, p1, -3.0f);
  o.z = fmaf(2.0f, p2, -3.0f);
  o.w = fmaf(2.0f, p3, -3.0f);
  out[i] = o;
}

// ---------------------------------------------------------------------------
// Fallback B (no usable ws): gather f32 features directly.
// ---------------------------------------------------------------------------
__device__ __forceinline__ void plane_accum_f(
    const float4* __restrict__ t, float a, float b,
    float& p0, float& p1, float& p2, float& p3) {
  float sa = a * 512.0f, sb = b * 512.0f;
  float fa = floorf(sa), fb = floorf(sb);
  float wa = sa - fa, wb = sb - fb;
  uint32_t ia = (uint32_t)fa, ib = (uint32_t)fb;
  uint32_t hb0 = ib * PRIME;
  uint32_t hb1 = hb0 + PRIME;
  uint32_t i00 = (ia ^ hb0) & TABLE_MASK;
  uint32_t i01 = (ia ^ hb1) & TABLE_MASK;
  uint32_t i10 = ((ia + 1u) ^ hb0) & TABLE_MASK;
  uint32_t i11 = ((ia + 1u) ^ hb1) & TABLE_MASK;
  float4 f00 = t[i00], f01 = t[i01], f10 = t[i10], f11 = t[i11];
  float omwa = 1.0f - wa, omwb = 1.0f - wb;
  float v00 = omwa * omwb, v01 = omwa * wb, v10 = wa * omwb, v11 = wa * wb;
#define ACCF(F, W)                                                            \
  p0 += ((F).x >= 0.0f) ? (W) : 0.0f;                                         \
  p1 += ((F).y >= 0.0f) ? (W) : 0.0f;                                         \
  p2 += ((F).z >= 0.0f) ? (W) : 0.0f;                                         \
  p3 += ((F).w >= 0.0f) ? (W) : 0.0f;
  ACCF(f00, v00)
  ACCF(f01, v01)
  ACCF(f10, v10)
  ACCF(f11, v11)
#undef ACCF
}

__global__ __launch_bounds__(256) void hash_direct(
    const float* __restrict__ pos, const float4* __restrict__ txy,
    const float4* __restrict__ txz, const float4* __restrict__ tyz,
    float4* __restrict__ out, int n) {
  int i = (int)(blockIdx.x * 256u + threadIdx.x);
  if (i >= n) return;
  float x = pos[3 * i + 0];
  float y = pos[3 * i + 1];
  float z = pos[3 * i + 2];
  float p0 = 0.f, p1 = 0.f, p2 = 0.f, p3 = 0.f;
  plane_accum_f(txy, x, y, p0, p1, p2, p3);
  plane_accum_f(txz, x, z, p0, p1, p2, p3);
  plane_accum_f(tyz, y, z, p0, p1, p2, p3);
  float4 o;
  o.x = fmaf(2.0f, p0, -3.0f);
  o.y = fmaf(2.0f, p1, -3.0f);
  o.z = fmaf(2.0f, p2, -3.0f);
  o.w = fmaf(2.0f, p3, -3.0f);
  out[i] = o;
}

extern "C" void kernel_launch(void* const* d_in, const int* in_sizes, int n_in,
                              void* d_out, int out_size, void* d_ws,
                              size_t ws_size, hipStream_t stream) {
  const float* pos = (const float*)d_in[0];
  const float* txy = (const float*)d_in[1];
  const float* txz = (const float*)d_in[2];
  const float* tyz = (const float*)d_in[3];
  float4* out = (float4*)d_out;
  int n = in_sizes[0] / 3;                       // 4194304
  int nblk = (n + 255) / 256;
  const size_t pk_bytes = (size_t)3 * WORDS_PER_TABLE * 4;        // 768 KB
  const size_t cell_bytes = (size_t)3 * CELLS_PER_PLANE * 2;      // 1.5 MB
  if (ws_size >= pk_bytes + cell_bytes) {
    uint32_t* pk = (uint32_t*)d_ws;
    uint16_t* cells = (uint16_t*)((char*)d_ws + pk_bytes);
    pack_kernel<<<3 * WORDS_PER_TABLE / 256, 256, 0, stream>>>(txy, txz, tyz,
                                                               pk);
    cellify_kernel<<<3 * CELLS_PER_PLANE / 256, 256, 0, stream>>>(pk, cells);
    hash_main<<<nblk, 256, 0, stream>>>(pos, cells, out, n);
  } else if (ws_size >= pk_bytes) {
    uint32_t* pk = (uint32_t*)d_ws;
    pack_kernel<<<3 * WORDS_PER_TABLE / 256, 256, 0, stream>>>(txy, txz, tyz,
                                                               pk);
    hash_packed<<<nblk, 256, 0, stream>>>(pos, pk, out, n);
  } else {
    hash_direct<<<nblk, 256, 0, stream>>>(pos, (const float4*)txy,
                                          (const float4*)txz,
                                          (const float4*)tyz, out, n);
  }
}